// Round 1
// baseline (1265.142 us; speedup 1.0000x reference)
//
#include <hip/hip_runtime.h>
#include <hip/hip_bf16.h>

// LIF multi-compartment refractory cell step.
// B=4096 batch, H=2048 hidden, I=2048 input. All fp32 in/out.
//
// Decomposition:
//   P0 = v @ g^T               (coupling)  -> z_new, v_new, rho_new (fused epilogue)
//   Pi = inp @ Wi^T + z @ Wr^T (K=4096)    -> i_new                 (fused epilogue)
// Spike decision v_decayed > 1 needs ~fp64 fidelity; GEMMs run in f16 MFMA
// (err sigma ~3e-4) and elements with |v_decayed-1| < 0.02 (non-refractory
// only) are recomputed exactly in fp64 by a fixup kernel.

#define HDIM 2048
#define BATCH 4096
#define KIN 2048

typedef _Float16 f16x8 __attribute__((ext_vector_type(8)));
typedef _Float16 f16x4 __attribute__((ext_vector_type(4)));
typedef float f32x4 __attribute__((ext_vector_type(4)));

#define BM 128
#define BN 128
#define BK 32
#define LDSP 40  // 32 + 8 f16 pad: row stride 80B keeps 16B alignment, breaks conflicts

#define MARGIN 0.02f

// Stage a BMx32 fp32 tile -> f16 LDS tile [row][k]. 256 threads.
__device__ __forceinline__ void stage_tile(const float* __restrict__ Ag, int lda,
                                           int row0, int k0,
                                           _Float16 (*As)[LDSP], int t) {
  int r = t >> 3;             // 0..31
  int c = (t & 7) * 4;        // 0,4,...,28
  #pragma unroll
  for (int rr = 0; rr < BM; rr += 32) {
    const float4 vv = *(const float4*)(Ag + (size_t)(row0 + rr + r) * lda + k0 + c);
    f16x4 h;
    h.x = (_Float16)vv.x; h.y = (_Float16)vv.y;
    h.z = (_Float16)vv.z; h.w = (_Float16)vv.w;
    *(f16x4*)&As[rr + r][c] = h;
  }
}

// ---------------- coupling GEMM + LIF epilogue (z, v, rho outputs) -------------
__global__ __launch_bounds__(256, 2)
void k_coupling(const float* __restrict__ v, const float* __restrict__ cur,
                const float* __restrict__ rho, const float* __restrict__ g,
                float* __restrict__ z_out, float* __restrict__ v_out,
                float* __restrict__ rho_out,
                unsigned* __restrict__ flag_cnt, unsigned* __restrict__ flag_list,
                unsigned flag_cap) {
  __shared__ _Float16 As[BM][LDSP];
  __shared__ _Float16 Bs[BN][LDSP];
  const int t = threadIdx.x;
  const int m0 = blockIdx.y * BM, n0 = blockIdx.x * BN;
  const int wave = t >> 6, lane = t & 63;
  const int wm = (wave >> 1) * 64, wn = (wave & 1) * 64;
  const int lrow = lane & 15, quad = lane >> 4, koff = quad * 8;

  f32x4 acc[4][4] = {};
  for (int k0 = 0; k0 < KIN; k0 += BK) {
    __syncthreads();
    stage_tile(v, KIN, m0, k0, As, t);
    stage_tile(g, KIN, n0, k0, Bs, t);
    __syncthreads();
    f16x8 af[4], bf[4];
    #pragma unroll
    for (int mi = 0; mi < 4; mi++) af[mi] = *(const f16x8*)&As[wm + mi * 16 + lrow][koff];
    #pragma unroll
    for (int ni = 0; ni < 4; ni++) bf[ni] = *(const f16x8*)&Bs[wn + ni * 16 + lrow][koff];
    #pragma unroll
    for (int mi = 0; mi < 4; mi++)
      #pragma unroll
      for (int ni = 0; ni < 4; ni++)
        acc[mi][ni] = __builtin_amdgcn_mfma_f32_16x16x32_f16(af[mi], bf[ni], acc[mi][ni], 0, 0, 0);
  }

  // Fused epilogue. C/D layout: col = lane&15, row = quad*4 + reg.
  #pragma unroll
  for (int mi = 0; mi < 4; mi++) {
    #pragma unroll
    for (int r = 0; r < 4; r++) {
      const int row = m0 + wm + mi * 16 + quad * 4 + r;
      #pragma unroll
      for (int ni = 0; ni < 4; ni++) {
        const int col = n0 + wn + ni * 16 + lrow;
        const size_t idx = (size_t)row * HDIM + col;
        const float P = acc[mi][ni][r];
        const float vv = v[idx], ii = cur[idx], rr = rho[idx];
        const float vd = vv + 0.1f * (ii - vv) + P;  // fl(0.001f*100f) == 0.1f
        float zo, vo, ro;
        if (rr > 0.0f) {              // refractory: hold v, suppress spike
          zo = 0.0f; vo = vv; ro = fmaxf(rr - 1.0f, 0.0f);
        } else {
          const bool zs = vd > 1.0f;
          zo = zs ? 1.0f : 0.0f;
          vo = zs ? 0.0f : vd;
          ro = zs ? 5.0f : fmaxf(rr, 0.0f);
          if (fabsf(vd - 1.0f) < MARGIN) {  // near threshold: exact recompute later
            unsigned p = atomicAdd(flag_cnt, 1u);
            if (p < flag_cap) flag_list[p] = (unsigned)idx;
          }
        }
        z_out[idx] = zo; v_out[idx] = vo; rho_out[idx] = ro;
      }
    }
  }
}

// ---------------- concat-K GEMM + i_new epilogue -------------------------------
__global__ __launch_bounds__(256, 2)
void k_current(const float* __restrict__ inp, const float* __restrict__ z,
               const float* __restrict__ cur,
               const float* __restrict__ Wi, const float* __restrict__ Wr,
               float* __restrict__ i_out) {
  __shared__ _Float16 As[BM][LDSP];
  __shared__ _Float16 Bs[BN][LDSP];
  const int t = threadIdx.x;
  const int m0 = blockIdx.y * BM, n0 = blockIdx.x * BN;
  const int wave = t >> 6, lane = t & 63;
  const int wm = (wave >> 1) * 64, wn = (wave & 1) * 64;
  const int lrow = lane & 15, quad = lane >> 4, koff = quad * 8;

  f32x4 acc[4][4] = {};
  for (int k0 = 0; k0 < 2 * KIN; k0 += BK) {
    const float* Ap; const float* Bp; int kl;
    if (k0 < KIN) { Ap = inp; Bp = Wi; kl = k0; }
    else          { Ap = z;   Bp = Wr; kl = k0 - KIN; }
    __syncthreads();
    stage_tile(Ap, KIN, m0, kl, As, t);
    stage_tile(Bp, KIN, n0, kl, Bs, t);
    __syncthreads();
    f16x8 af[4], bf[4];
    #pragma unroll
    for (int mi = 0; mi < 4; mi++) af[mi] = *(const f16x8*)&As[wm + mi * 16 + lrow][koff];
    #pragma unroll
    for (int ni = 0; ni < 4; ni++) bf[ni] = *(const f16x8*)&Bs[wn + ni * 16 + lrow][koff];
    #pragma unroll
    for (int mi = 0; mi < 4; mi++)
      #pragma unroll
      for (int ni = 0; ni < 4; ni++)
        acc[mi][ni] = __builtin_amdgcn_mfma_f32_16x16x32_f16(af[mi], bf[ni], acc[mi][ni], 0, 0, 0);
  }

  #pragma unroll
  for (int mi = 0; mi < 4; mi++) {
    #pragma unroll
    for (int r = 0; r < 4; r++) {
      const int row = m0 + wm + mi * 16 + quad * 4 + r;
      #pragma unroll
      for (int ni = 0; ni < 4; ni++) {
        const int col = n0 + wn + ni * 16 + lrow;
        const size_t idx = (size_t)row * HDIM + col;
        const float ii = cur[idx];
        i_out[idx] = (ii - 0.2f * ii) + acc[mi][ni][r];  // i_decayed + (P1+P2)
      }
    }
  }
}

// ---------------- fp64 exact recompute of near-threshold neurons ---------------
__global__ __launch_bounds__(256, 2)
void k_fixup(const float* __restrict__ v, const float* __restrict__ cur,
             const float* __restrict__ rho, const float* __restrict__ g,
             float* __restrict__ z_out, float* __restrict__ v_out,
             float* __restrict__ rho_out,
             const unsigned* __restrict__ flag_cnt,
             const unsigned* __restrict__ flag_list, unsigned flag_cap) {
  unsigned n = *flag_cnt;
  if (n > flag_cap) n = flag_cap;
  const int lane = threadIdx.x & 63;
  const int nw = gridDim.x * 4;
  for (unsigned it = blockIdx.x * 4 + (threadIdx.x >> 6); it < n; it += nw) {
    const unsigned idx = flag_list[it];
    const unsigned b = idx >> 11, h = idx & (HDIM - 1);
    const float* vp = v + (size_t)b * HDIM;
    const float* gp = g + (size_t)h * HDIM;
    double s = 0.0;
    for (int k = lane; k < KIN; k += 64)
      s += (double)vp[k] * (double)gp[k];
    #pragma unroll
    for (int off = 32; off; off >>= 1)
      s += __shfl_down(s, off, 64);
    if (lane == 0) {
      const double vv = (double)v[idx], ii = (double)cur[idx];
      const double vd = (vv + (0.001 * 100.0) * ((0.0 - vv) + ii)) + s;
      const bool zs = vd > 1.0;
      // flagged elements are guaranteed non-refractory (rho <= 0)
      z_out[idx]   = zs ? 1.0f : 0.0f;
      v_out[idx]   = zs ? 0.0f : (float)vd;
      rho_out[idx] = zs ? 5.0f : fmaxf(rho[idx], 0.0f);
    }
  }
}

__global__ void k_zero_cnt(unsigned* p) { if (threadIdx.x == 0) p[0] = 0; }

extern "C" void kernel_launch(void* const* d_in, const int* in_sizes, int n_in,
                              void* d_out, int out_size, void* d_ws, size_t ws_size,
                              hipStream_t stream) {
  (void)in_sizes; (void)n_in; (void)out_size;
  const float* inp = (const float*)d_in[0];
  const float* z   = (const float*)d_in[1];
  const float* v   = (const float*)d_in[2];
  const float* cur = (const float*)d_in[3];
  const float* rho = (const float*)d_in[4];
  const float* Wi  = (const float*)d_in[5];
  const float* Wr  = (const float*)d_in[6];
  const float* g   = (const float*)d_in[7];

  float* out = (float*)d_out;
  const size_t NE = (size_t)BATCH * HDIM;
  float* z_out   = out;
  float* v_out   = out + NE;
  float* i_out   = out + 2 * NE;
  float* rho_out = out + 3 * NE;

  unsigned* flag_cnt  = (unsigned*)d_ws;
  unsigned* flag_list = (unsigned*)d_ws + 4;
  unsigned flag_cap = 0;
  if (ws_size > 64) {
    size_t cap = (ws_size - 16) / sizeof(unsigned);
    if (cap > (size_t)4 * 1024 * 1024) cap = (size_t)4 * 1024 * 1024;
    flag_cap = (unsigned)cap;
  }

  k_zero_cnt<<<1, 64, 0, stream>>>(flag_cnt);
  dim3 grid(HDIM / BN, BATCH / BM);
  k_coupling<<<grid, 256, 0, stream>>>(v, cur, rho, g, z_out, v_out, rho_out,
                                       flag_cnt, flag_list, flag_cap);
  k_current<<<grid, 256, 0, stream>>>(inp, z, cur, Wi, Wr, i_out);
  k_fixup<<<256, 256, 0, stream>>>(v, cur, rho, g, z_out, v_out, rho_out,
                                   flag_cnt, flag_list, flag_cap);
}

// Round 3
// 1173.253 us; speedup vs baseline: 1.0783x; 1.0783x over previous
//
#include <hip/hip_runtime.h>

// LIF multi-compartment refractory cell step. B=4096, H=I=2048, fp32 in/out.
//
// Round 3 = round 2 with the cvt_pkrtz return-type compile fix.
//  - k_init:  i_out = i_decayed, zero flag counter
//  - k_cast:  fp32 -> f16 copies of {v,inp,z,g,Wi,Wr} into d_ws (if it fits)
//  - k_gemm<T>: 1536 blocks, 3 roles x 512 tiles (128x128, BK=32):
//       role 0: v@g^T      -> fused LIF epilogue (z,v,rho) + near-threshold flags
//       role 1: inp@Wi^T   -> atomicAdd into i_out
//       role 2: z@Wr^T     -> atomicAdd into i_out
//    staging via global_load_lds(16B), XOR-swizzled LDS for conflict-free b128 reads
//  - k_fixup: exact fp64 recompute of |v_decayed-1|<0.02 non-refractory neurons

#define HDIM 2048
#define BATCH 4096
#define KIN 2048
#define BM 128
#define BN 128
#define BK 32
#define MARGIN 0.02f

typedef _Float16 f16x8 __attribute__((ext_vector_type(8)));
typedef __fp16 h16x2 __attribute__((ext_vector_type(2)));   // cvt_pkrtz return type
typedef float f32x4 __attribute__((ext_vector_type(4)));

// ---- staging: global -> LDS via 16B DMA, lane-contiguous LDS, XOR-swizzled source --
template <typename T>
__device__ __forceinline__ void stage(const T* src, int ldk, int row0, int k0,
                                      T* lds_tile, int t) {
  constexpr int CHN = (BK * (int)sizeof(T)) / 16;  // 16B chunks per row (4 f16 / 8 f32)
  constexpr int EPC = 16 / (int)sizeof(T);         // elements per chunk
#pragma unroll
  for (int j = 0; j < (BM * CHN) / 256; ++j) {
    const int u = j * 256 + t;                     // LDS chunk slot (lane-contiguous)
    const int r = u / CHN;
    const int cs = u & (CHN - 1);
    const int c = cs ^ (((r * CHN) >> 3) & (CHN - 1));  // swizzle: f16 (r>>1)&3, f32 r&7
    const T* g = src + (size_t)(row0 + r) * ldk + k0 + c * EPC;
    __builtin_amdgcn_global_load_lds(
        (const __attribute__((address_space(1))) void*)(T*)g,
        (__attribute__((address_space(3))) void*)(lds_tile + u * EPC), 16, 0, 0);
  }
}

// ---- fragment readers (undo the swizzle) ------------------------------------------
__device__ __forceinline__ f16x8 read_frag(const _Float16* tile, int r, int q) {
  const int slot = r * 4 + (q ^ ((r >> 1) & 3));
  return *(const f16x8*)(tile + slot * 8);
}
__device__ __forceinline__ f16x8 read_frag(const float* tile, int r, int q) {
  const int s = r & 7;
  const f32x4 a = *(const f32x4*)(tile + (r * 8 + ((2 * q) ^ s)) * 4);
  const f32x4 b = *(const f32x4*)(tile + (r * 8 + ((2 * q + 1) ^ s)) * 4);
  f16x8 o;
  h16x2 p;
  p = __builtin_amdgcn_cvt_pkrtz(a[0], a[1]); o[0] = (_Float16)p[0]; o[1] = (_Float16)p[1];
  p = __builtin_amdgcn_cvt_pkrtz(a[2], a[3]); o[2] = (_Float16)p[0]; o[3] = (_Float16)p[1];
  p = __builtin_amdgcn_cvt_pkrtz(b[0], b[1]); o[4] = (_Float16)p[0]; o[5] = (_Float16)p[1];
  p = __builtin_amdgcn_cvt_pkrtz(b[2], b[3]); o[6] = (_Float16)p[0]; o[7] = (_Float16)p[1];
  return o;
}

// ---- fused GEMM: 3 roles ----------------------------------------------------------
template <typename T>
__global__ __launch_bounds__(256, 4)
void k_gemm(const T* vA, const T* inpA, const T* zA,
            const T* gB, const T* WiB, const T* WrB,
            const float* v, const float* cur, const float* rho,
            float* z_out, float* v_out, float* rho_out, float* i_out,
            unsigned* flag_cnt, unsigned* flag_list, unsigned flag_cap) {
  __shared__ T As[BM * BK];
  __shared__ T Bs[BN * BK];
  const int t = threadIdx.x;
  const int bid = blockIdx.x;
  const int role = bid % 3;
  const int tb = bid / 3;
  const int n0 = (tb & 15) * BN;   // 2048/128 = 16 N-tiles
  const int m0 = (tb >> 4) * BM;   // 32 M-tiles
  const T* Ap = (role == 0) ? vA : (role == 1) ? inpA : zA;
  const T* Bp = (role == 0) ? gB : (role == 1) ? WiB : WrB;

  const int wave = t >> 6, lane = t & 63;
  const int wm = (wave >> 1) * 64, wn = (wave & 1) * 64;
  const int lrow = lane & 15, quad = lane >> 4;

  f32x4 acc[4][4] = {};
  for (int k0 = 0; k0 < KIN; k0 += BK) {
    __syncthreads();                       // previous iter's frag reads done
    stage(Ap, KIN, m0, k0, As, t);
    stage(Bp, KIN, n0, k0, Bs, t);
    __syncthreads();                       // drains vmcnt (gll complete)
    f16x8 af[4], bf[4];
#pragma unroll
    for (int mi = 0; mi < 4; ++mi) af[mi] = read_frag(As, wm + mi * 16 + lrow, quad);
#pragma unroll
    for (int ni = 0; ni < 4; ++ni) bf[ni] = read_frag(Bs, wn + ni * 16 + lrow, quad);
#pragma unroll
    for (int mi = 0; mi < 4; ++mi)
#pragma unroll
      for (int ni = 0; ni < 4; ++ni)
        acc[mi][ni] =
            __builtin_amdgcn_mfma_f32_16x16x32_f16(af[mi], bf[ni], acc[mi][ni], 0, 0, 0);
  }

  // C/D layout: col = lane&15, row = quad*4 + reg
  if (role == 0) {
#pragma unroll
    for (int mi = 0; mi < 4; ++mi)
#pragma unroll
      for (int r = 0; r < 4; ++r) {
        const int row = m0 + wm + mi * 16 + quad * 4 + r;
#pragma unroll
        for (int ni = 0; ni < 4; ++ni) {
          const int col = n0 + wn + ni * 16 + lrow;
          const size_t idx = (size_t)row * HDIM + col;
          const float P = acc[mi][ni][r];
          const float vv = v[idx], ii = cur[idx], rr = rho[idx];
          const float vd = vv + 0.1f * (ii - vv) + P;
          float zo, vo, ro;
          if (rr > 0.0f) {  // refractory: hold v, suppress spike
            zo = 0.0f; vo = vv; ro = fmaxf(rr - 1.0f, 0.0f);
          } else {
            const bool zs = vd > 1.0f;
            zo = zs ? 1.0f : 0.0f;
            vo = zs ? 0.0f : vd;
            ro = zs ? 5.0f : fmaxf(rr, 0.0f);
            if (fabsf(vd - 1.0f) < MARGIN) {
              unsigned p = atomicAdd(flag_cnt, 1u);
              if (p < flag_cap) flag_list[p] = (unsigned)idx;
            }
          }
          z_out[idx] = zo; v_out[idx] = vo; rho_out[idx] = ro;
        }
      }
  } else {
#pragma unroll
    for (int mi = 0; mi < 4; ++mi)
#pragma unroll
      for (int r = 0; r < 4; ++r) {
        const int row = m0 + wm + mi * 16 + quad * 4 + r;
#pragma unroll
        for (int ni = 0; ni < 4; ++ni) {
          const int col = n0 + wn + ni * 16 + lrow;
          atomicAdd(i_out + (size_t)row * HDIM + col, acc[mi][ni][r]);
        }
      }
  }
}

// ---- i_out = i_decayed, zero flag counter ----------------------------------------
__global__ void k_init(const float* __restrict__ cur, float* __restrict__ i_out,
                       unsigned* __restrict__ flag_cnt) {
  const size_t w = (size_t)blockIdx.x * blockDim.x + threadIdx.x;
  if (w == 0) *flag_cnt = 0;
  const size_t N4 = (size_t)BATCH * HDIM / 4;
  if (w < N4) {
    f32x4 c = *(const f32x4*)(cur + w * 4);
    f32x4 o;
    o[0] = c[0] - 0.2f * c[0]; o[1] = c[1] - 0.2f * c[1];
    o[2] = c[2] - 0.2f * c[2]; o[3] = c[3] - 0.2f * c[3];
    *(f32x4*)(i_out + w * 4) = o;
  }
}

// ---- fp32 -> f16 cast of all six GEMM operands into ws ---------------------------
__global__ void k_cast(const float* __restrict__ v, const float* __restrict__ inp,
                       const float* __restrict__ z, const float* __restrict__ g,
                       const float* __restrict__ Wi, const float* __restrict__ Wr,
                       _Float16* __restrict__ dst) {
  const size_t NA = (size_t)BATCH * HDIM, NB = (size_t)HDIM * HDIM;
  const size_t TOT = (3 * NA + 3 * NB) / 8;
  const size_t w = (size_t)blockIdx.x * blockDim.x + threadIdx.x;
  if (w >= TOT) return;
  const size_t e = w * 8;
  const float* s; size_t off;
  if      (e < NA)          { s = v;   off = e; }
  else if (e < 2 * NA)      { s = inp; off = e - NA; }
  else if (e < 3 * NA)      { s = z;   off = e - 2 * NA; }
  else if (e < 3 * NA + NB) { s = g;   off = e - 3 * NA; }
  else if (e < 3 * NA + 2 * NB) { s = Wi; off = e - 3 * NA - NB; }
  else                      { s = Wr;  off = e - 3 * NA - 2 * NB; }
  const f32x4 a = *(const f32x4*)(s + off);
  const f32x4 b = *(const f32x4*)(s + off + 4);
  f16x8 o; h16x2 p;
  p = __builtin_amdgcn_cvt_pkrtz(a[0], a[1]); o[0] = (_Float16)p[0]; o[1] = (_Float16)p[1];
  p = __builtin_amdgcn_cvt_pkrtz(a[2], a[3]); o[2] = (_Float16)p[0]; o[3] = (_Float16)p[1];
  p = __builtin_amdgcn_cvt_pkrtz(b[0], b[1]); o[4] = (_Float16)p[0]; o[5] = (_Float16)p[1];
  p = __builtin_amdgcn_cvt_pkrtz(b[2], b[3]); o[6] = (_Float16)p[0]; o[7] = (_Float16)p[1];
  *(f16x8*)(dst + e) = o;
}

// ---- fp64 exact recompute of near-threshold neurons ------------------------------
__global__ __launch_bounds__(256, 2)
void k_fixup(const float* __restrict__ v, const float* __restrict__ cur,
             const float* __restrict__ rho, const float* __restrict__ g,
             float* __restrict__ z_out, float* __restrict__ v_out,
             float* __restrict__ rho_out,
             const unsigned* __restrict__ flag_cnt,
             const unsigned* __restrict__ flag_list, unsigned flag_cap) {
  unsigned n = *flag_cnt;
  if (n > flag_cap) n = flag_cap;
  const int lane = threadIdx.x & 63;
  const int nw = gridDim.x * 4;
  for (unsigned it = blockIdx.x * 4 + (threadIdx.x >> 6); it < n; it += nw) {
    const unsigned idx = flag_list[it];
    const unsigned b = idx >> 11, h = idx & (HDIM - 1);
    const float* vp = v + (size_t)b * HDIM;
    const float* gp = g + (size_t)h * HDIM;
    double s = 0.0;
    for (int k = lane; k < KIN; k += 64) s += (double)vp[k] * (double)gp[k];
#pragma unroll
    for (int off = 32; off; off >>= 1) s += __shfl_down(s, off, 64);
    if (lane == 0) {
      const double vv = (double)v[idx], ii = (double)cur[idx];
      const double vd = (vv + (0.001 * 100.0) * ((0.0 - vv) + ii)) + s;
      const bool zs = vd > 1.0;
      z_out[idx]   = zs ? 1.0f : 0.0f;       // flagged elems are non-refractory
      v_out[idx]   = zs ? 0.0f : (float)vd;
      rho_out[idx] = zs ? 5.0f : fmaxf(rho[idx], 0.0f);
    }
  }
}

extern "C" void kernel_launch(void* const* d_in, const int* in_sizes, int n_in,
                              void* d_out, int out_size, void* d_ws, size_t ws_size,
                              hipStream_t stream) {
  (void)in_sizes; (void)n_in; (void)out_size;
  const float* inp = (const float*)d_in[0];
  const float* z   = (const float*)d_in[1];
  const float* v   = (const float*)d_in[2];
  const float* cur = (const float*)d_in[3];
  const float* rho = (const float*)d_in[4];
  const float* Wi  = (const float*)d_in[5];
  const float* Wr  = (const float*)d_in[6];
  const float* g   = (const float*)d_in[7];

  float* out = (float*)d_out;
  const size_t NE = (size_t)BATCH * HDIM;
  float* z_out = out;
  float* v_out = out + NE;
  float* i_out = out + 2 * NE;
  float* rho_out = out + 3 * NE;

  const size_t NA = NE, NB = (size_t)HDIM * HDIM;
  const size_t F16_NEED = (3 * NA + 3 * NB) * sizeof(_Float16);  // ~72 MB
  const bool use16 = ws_size >= F16_NEED + (1u << 22);

  unsigned* flag_cnt =
      use16 ? (unsigned*)((char*)d_ws + F16_NEED) : (unsigned*)d_ws;
  unsigned* flag_list = flag_cnt + 4;
  unsigned flag_cap = 0;
  {
    const size_t used = (size_t)((char*)flag_list - (char*)d_ws);
    if (ws_size > used + 64) {
      size_t cap = (ws_size - used) / sizeof(unsigned);
      if (cap > (size_t)4 * 1024 * 1024) cap = (size_t)4 * 1024 * 1024;
      flag_cap = (unsigned)cap;
    }
  }

  k_init<<<(unsigned)(NE / 4 / 256), 256, 0, stream>>>(cur, i_out, flag_cnt);

  if (use16) {
    _Float16* ws16 = (_Float16*)d_ws;
    const _Float16* vh   = ws16;
    const _Float16* inph = ws16 + NA;
    const _Float16* zh   = ws16 + 2 * NA;
    const _Float16* gh   = ws16 + 3 * NA;
    const _Float16* Wih  = ws16 + 3 * NA + NB;
    const _Float16* Wrh  = ws16 + 3 * NA + 2 * NB;
    const size_t TOT = (3 * NA + 3 * NB) / 8;
    k_cast<<<(unsigned)((TOT + 255) / 256), 256, 0, stream>>>(v, inp, z, g, Wi, Wr, ws16);
    k_gemm<_Float16><<<1536, 256, 0, stream>>>(vh, inph, zh, gh, Wih, Wrh,
                                               v, cur, rho, z_out, v_out, rho_out, i_out,
                                               flag_cnt, flag_list, flag_cap);
  } else {
    k_gemm<float><<<1536, 256, 0, stream>>>(v, inp, z, g, Wi, Wr,
                                            v, cur, rho, z_out, v_out, rho_out, i_out,
                                            flag_cnt, flag_list, flag_cap);
  }

  k_fixup<<<256, 256, 0, stream>>>(v, cur, rho, g, z_out, v_out, rho_out,
                                   flag_cnt, flag_list, flag_cap);
}

// Round 4
// 881.503 us; speedup vs baseline: 1.4352x; 1.3310x over previous
//
#include <hip/hip_runtime.h>

// LIF multi-compartment refractory cell step. B=4096, H=I=2048, fp32 in/out.
//
// Round 4:
//  - k_cast: fp32 -> f16 of {v,inp,z,g,Wi,Wr} into d_ws; zeroes flag counter
//  - k_gemm<T>: 1024 blocks, 2 roles (XCD-aware mapping, no atomics):
//      role 0: v@g^T  (K=2048)          -> fused LIF epilogue (z,v,rho) + flags
//      role 1: inp@Wi^T + z@Wr^T (K=4096 concat) -> i_new = i_decayed + acc
//    staging via global_load_lds(16B), XOR-swizzled LDS, conflict-free b128 reads
//  - k_fixup: exact fp64 recompute of |v_decayed-1|<0.02 non-refractory neurons

#define HDIM 2048
#define BATCH 4096
#define KIN 2048
#define BM 128
#define BN 128
#define BK 32
#define MARGIN 0.02f

typedef _Float16 f16x8 __attribute__((ext_vector_type(8)));
typedef __fp16 h16x2 __attribute__((ext_vector_type(2)));   // cvt_pkrtz return type
typedef float f32x4 __attribute__((ext_vector_type(4)));

// ---- staging: global -> LDS via 16B DMA, lane-contiguous LDS, XOR-swizzled source --
template <typename T>
__device__ __forceinline__ void stage(const T* src, int ldk, int row0, int k0,
                                      T* lds_tile, int t) {
  constexpr int CHN = (BK * (int)sizeof(T)) / 16;  // 16B chunks per row (4 f16 / 8 f32)
  constexpr int EPC = 16 / (int)sizeof(T);         // elements per chunk
#pragma unroll
  for (int j = 0; j < (BM * CHN) / 256; ++j) {
    const int u = j * 256 + t;                     // LDS chunk slot (lane-contiguous)
    const int r = u / CHN;
    const int cs = u & (CHN - 1);
    const int c = cs ^ (((r * CHN) >> 3) & (CHN - 1));  // swizzle: f16 (r>>1)&3, f32 r&7
    const T* g = src + (size_t)(row0 + r) * ldk + k0 + c * EPC;
    __builtin_amdgcn_global_load_lds(
        (const __attribute__((address_space(1))) void*)(T*)g,
        (__attribute__((address_space(3))) void*)(lds_tile + u * EPC), 16, 0, 0);
  }
}

// ---- fragment readers (undo the swizzle) ------------------------------------------
__device__ __forceinline__ f16x8 read_frag(const _Float16* tile, int r, int q) {
  const int slot = r * 4 + (q ^ ((r >> 1) & 3));
  return *(const f16x8*)(tile + slot * 8);
}
__device__ __forceinline__ f16x8 read_frag(const float* tile, int r, int q) {
  const int s = r & 7;
  const f32x4 a = *(const f32x4*)(tile + (r * 8 + ((2 * q) ^ s)) * 4);
  const f32x4 b = *(const f32x4*)(tile + (r * 8 + ((2 * q + 1) ^ s)) * 4);
  f16x8 o;
  h16x2 p;
  p = __builtin_amdgcn_cvt_pkrtz(a[0], a[1]); o[0] = (_Float16)p[0]; o[1] = (_Float16)p[1];
  p = __builtin_amdgcn_cvt_pkrtz(a[2], a[3]); o[2] = (_Float16)p[0]; o[3] = (_Float16)p[1];
  p = __builtin_amdgcn_cvt_pkrtz(b[0], b[1]); o[4] = (_Float16)p[0]; o[5] = (_Float16)p[1];
  p = __builtin_amdgcn_cvt_pkrtz(b[2], b[3]); o[6] = (_Float16)p[0]; o[7] = (_Float16)p[1];
  return o;
}

// ---- fused GEMM: 2 roles, XCD-aware tile mapping ----------------------------------
template <typename T>
__global__ __launch_bounds__(256, 4)
void k_gemm(const T* vA, const T* inpA, const T* zA,
            const T* gB, const T* WiB, const T* WrB,
            const float* v, const float* cur, const float* rho,
            float* z_out, float* v_out, float* rho_out, float* i_out,
            unsigned* flag_cnt, unsigned* flag_list, unsigned flag_cap) {
  __shared__ T As[BM * BK];
  __shared__ T Bs[BN * BK];
  const int t = threadIdx.x;
  const int bid = blockIdx.x;
  // XCD-aware: round-robin dispatch puts bid%8 on XCD bid%8. Give each XCD a
  // 4-M-tile stripe per role so staging panels stay in its private L2.
  const int x = bid & 7;            // XCD
  const int j = bid >> 3;           // 0..127 within XCD
  const int role = j & 1;           // interleave roles for even CU mixing
  const int jj = j >> 1;            // 0..63
  const int n0 = (jj & 15) * BN;    // 16 N-tiles
  const int m0 = (x * 4 + (jj >> 4)) * BM;  // 32 M-tiles, stripe x*4..x*4+3

  const int wave = t >> 6, lane = t & 63;
  const int wm = (wave >> 1) * 64, wn = (wave & 1) * 64;
  const int lrow = lane & 15, quad = lane >> 4;

  const int kmax = role ? 2 * KIN : KIN;
  f32x4 acc[4][4] = {};
  for (int k0 = 0; k0 < kmax; k0 += BK) {
    const T* Ap; const T* Bp;
    if (role == 0)      { Ap = vA;   Bp = gB;  }
    else if (k0 < KIN)  { Ap = inpA; Bp = WiB; }
    else                { Ap = zA;   Bp = WrB; }
    const int kl = k0 & (KIN - 1);
    __syncthreads();                       // previous iter's frag reads done
    stage(Ap, KIN, m0, kl, As, t);
    stage(Bp, KIN, n0, kl, Bs, t);
    __syncthreads();                       // drains vmcnt (gll complete)
    f16x8 af[4], bf[4];
#pragma unroll
    for (int mi = 0; mi < 4; ++mi) af[mi] = read_frag(As, wm + mi * 16 + lrow, quad);
#pragma unroll
    for (int ni = 0; ni < 4; ++ni) bf[ni] = read_frag(Bs, wn + ni * 16 + lrow, quad);
#pragma unroll
    for (int mi = 0; mi < 4; ++mi)
#pragma unroll
      for (int ni = 0; ni < 4; ++ni)
        acc[mi][ni] =
            __builtin_amdgcn_mfma_f32_16x16x32_f16(af[mi], bf[ni], acc[mi][ni], 0, 0, 0);
  }

  // C/D layout: col = lane&15, row = quad*4 + reg
  if (role == 0) {
#pragma unroll
    for (int mi = 0; mi < 4; ++mi)
#pragma unroll
      for (int r = 0; r < 4; ++r) {
        const int row = m0 + wm + mi * 16 + quad * 4 + r;
#pragma unroll
        for (int ni = 0; ni < 4; ++ni) {
          const int col = n0 + wn + ni * 16 + lrow;
          const size_t idx = (size_t)row * HDIM + col;
          const float P = acc[mi][ni][r];
          const float vv = v[idx], ii = cur[idx], rr = rho[idx];
          const float vd = vv + 0.1f * (ii - vv) + P;
          float zo, vo, ro;
          if (rr > 0.0f) {  // refractory: hold v, suppress spike
            zo = 0.0f; vo = vv; ro = fmaxf(rr - 1.0f, 0.0f);
          } else {
            const bool zs = vd > 1.0f;
            zo = zs ? 1.0f : 0.0f;
            vo = zs ? 0.0f : vd;
            ro = zs ? 5.0f : fmaxf(rr, 0.0f);
            if (fabsf(vd - 1.0f) < MARGIN) {
              unsigned p = atomicAdd(flag_cnt, 1u);
              if (p < flag_cap) flag_list[p] = (unsigned)idx;
            }
          }
          z_out[idx] = zo; v_out[idx] = vo; rho_out[idx] = ro;
        }
      }
  } else {
#pragma unroll
    for (int mi = 0; mi < 4; ++mi)
#pragma unroll
      for (int r = 0; r < 4; ++r) {
        const int row = m0 + wm + mi * 16 + quad * 4 + r;
#pragma unroll
        for (int ni = 0; ni < 4; ++ni) {
          const int col = n0 + wn + ni * 16 + lrow;
          const size_t idx = (size_t)row * HDIM + col;
          const float ii = cur[idx];
          i_out[idx] = (ii - 0.2f * ii) + acc[mi][ni][r];  // i_decayed + inp@Wi^T + z@Wr^T
        }
      }
  }
}

// ---- fp32 -> f16 cast of all six GEMM operands into ws; zero flag counter --------
__global__ void k_cast(const float* __restrict__ v, const float* __restrict__ inp,
                       const float* __restrict__ z, const float* __restrict__ g,
                       const float* __restrict__ Wi, const float* __restrict__ Wr,
                       _Float16* __restrict__ dst, unsigned* __restrict__ flag_cnt) {
  if (blockIdx.x == 0 && threadIdx.x == 0) *flag_cnt = 0;
  const size_t NA = (size_t)BATCH * HDIM, NB = (size_t)HDIM * HDIM;
  const size_t TOT = (3 * NA + 3 * NB) / 8;
  const size_t w = (size_t)blockIdx.x * blockDim.x + threadIdx.x;
  if (w >= TOT) return;
  const size_t e = w * 8;
  const float* s; size_t off;
  if      (e < NA)          { s = v;   off = e; }
  else if (e < 2 * NA)      { s = inp; off = e - NA; }
  else if (e < 3 * NA)      { s = z;   off = e - 2 * NA; }
  else if (e < 3 * NA + NB) { s = g;   off = e - 3 * NA; }
  else if (e < 3 * NA + 2 * NB) { s = Wi; off = e - 3 * NA - NB; }
  else                      { s = Wr;  off = e - 3 * NA - 2 * NB; }
  const f32x4 a = *(const f32x4*)(s + off);
  const f32x4 b = *(const f32x4*)(s + off + 4);
  f16x8 o; h16x2 p;
  p = __builtin_amdgcn_cvt_pkrtz(a[0], a[1]); o[0] = (_Float16)p[0]; o[1] = (_Float16)p[1];
  p = __builtin_amdgcn_cvt_pkrtz(a[2], a[3]); o[2] = (_Float16)p[0]; o[3] = (_Float16)p[1];
  p = __builtin_amdgcn_cvt_pkrtz(b[0], b[1]); o[4] = (_Float16)p[0]; o[5] = (_Float16)p[1];
  p = __builtin_amdgcn_cvt_pkrtz(b[2], b[3]); o[6] = (_Float16)p[0]; o[7] = (_Float16)p[1];
  *(f16x8*)(dst + e) = o;
}

__global__ void k_zero_cnt(unsigned* p) { if (threadIdx.x == 0) p[0] = 0; }

// ---- fp64 exact recompute of near-threshold neurons ------------------------------
__global__ __launch_bounds__(256, 2)
void k_fixup(const float* __restrict__ v, const float* __restrict__ cur,
             const float* __restrict__ rho, const float* __restrict__ g,
             float* __restrict__ z_out, float* __restrict__ v_out,
             float* __restrict__ rho_out,
             const unsigned* __restrict__ flag_cnt,
             const unsigned* __restrict__ flag_list, unsigned flag_cap) {
  unsigned n = *flag_cnt;
  if (n > flag_cap) n = flag_cap;
  const int lane = threadIdx.x & 63;
  const int nw = gridDim.x * 4;
  for (unsigned it = blockIdx.x * 4 + (threadIdx.x >> 6); it < n; it += nw) {
    const unsigned idx = flag_list[it];
    const unsigned b = idx >> 11, h = idx & (HDIM - 1);
    const float* vp = v + (size_t)b * HDIM;
    const float* gp = g + (size_t)h * HDIM;
    double s = 0.0;
    for (int k = lane; k < KIN; k += 64) s += (double)vp[k] * (double)gp[k];
#pragma unroll
    for (int off = 32; off; off >>= 1) s += __shfl_down(s, off, 64);
    if (lane == 0) {
      const double vv = (double)v[idx], ii = (double)cur[idx];
      const double vd = (vv + (0.001 * 100.0) * ((0.0 - vv) + ii)) + s;
      const bool zs = vd > 1.0;
      z_out[idx]   = zs ? 1.0f : 0.0f;       // flagged elems are non-refractory
      v_out[idx]   = zs ? 0.0f : (float)vd;
      rho_out[idx] = zs ? 5.0f : fmaxf(rho[idx], 0.0f);
    }
  }
}

extern "C" void kernel_launch(void* const* d_in, const int* in_sizes, int n_in,
                              void* d_out, int out_size, void* d_ws, size_t ws_size,
                              hipStream_t stream) {
  (void)in_sizes; (void)n_in; (void)out_size;
  const float* inp = (const float*)d_in[0];
  const float* z   = (const float*)d_in[1];
  const float* v   = (const float*)d_in[2];
  const float* cur = (const float*)d_in[3];
  const float* rho = (const float*)d_in[4];
  const float* Wi  = (const float*)d_in[5];
  const float* Wr  = (const float*)d_in[6];
  const float* g   = (const float*)d_in[7];

  float* out = (float*)d_out;
  const size_t NE = (size_t)BATCH * HDIM;
  float* z_out = out;
  float* v_out = out + NE;
  float* i_out = out + 2 * NE;
  float* rho_out = out + 3 * NE;

  const size_t NA = NE, NB = (size_t)HDIM * HDIM;
  const size_t F16_NEED = (3 * NA + 3 * NB) * sizeof(_Float16);  // ~72 MB
  const bool use16 = ws_size >= F16_NEED + (1u << 22);

  unsigned* flag_cnt =
      use16 ? (unsigned*)((char*)d_ws + F16_NEED) : (unsigned*)d_ws;
  unsigned* flag_list = flag_cnt + 4;
  unsigned flag_cap = 0;
  {
    const size_t used = (size_t)((char*)flag_list - (char*)d_ws);
    if (ws_size > used + 64) {
      size_t cap = (ws_size - used) / sizeof(unsigned);
      if (cap > (size_t)4 * 1024 * 1024) cap = (size_t)4 * 1024 * 1024;
      flag_cap = (unsigned)cap;
    }
  }

  if (use16) {
    _Float16* ws16 = (_Float16*)d_ws;
    const _Float16* vh   = ws16;
    const _Float16* inph = ws16 + NA;
    const _Float16* zh   = ws16 + 2 * NA;
    const _Float16* gh   = ws16 + 3 * NA;
    const _Float16* Wih  = ws16 + 3 * NA + NB;
    const _Float16* Wrh  = ws16 + 3 * NA + 2 * NB;
    const size_t TOT = (3 * NA + 3 * NB) / 8;
    k_cast<<<(unsigned)((TOT + 255) / 256), 256, 0, stream>>>(v, inp, z, g, Wi, Wr,
                                                              ws16, flag_cnt);
    k_gemm<_Float16><<<1024, 256, 0, stream>>>(vh, inph, zh, gh, Wih, Wrh,
                                               v, cur, rho, z_out, v_out, rho_out, i_out,
                                               flag_cnt, flag_list, flag_cap);
  } else {
    k_zero_cnt<<<1, 64, 0, stream>>>(flag_cnt);
    k_gemm<float><<<1024, 256, 0, stream>>>(v, inp, z, g, Wi, Wr,
                                            v, cur, rho, z_out, v_out, rho_out, i_out,
                                            flag_cnt, flag_list, flag_cap);
  }

  k_fixup<<<1024, 256, 0, stream>>>(v, cur, rho, g, z_out, v_out, rho_out,
                                    flag_cnt, flag_list, flag_cap);
}